// Round 6
// baseline (1417.087 us; speedup 1.0000x reference)
//
#include <hip/hip_runtime.h>
#include <cstdint>

#define B 4096
#define D 256
#define H 512
#define K 10
#define NL 4
#define S 10
#define NOUT 30           // used head columns per d (3*K); tail C=64 unused
#define HEADW 94          // 3*K + C
#define ND (B*D)          // 1048576
#define NFIN 7680         // D*NOUT
#define NLOG 2560         // D*K   logits columns (exact fp32)
#define NMS  5120         // D*2K  means+scales columns (MFMA path)

typedef __bf16 bf16x8 __attribute__((ext_vector_type(8)));
typedef float  f32x16 __attribute__((ext_vector_type(16)));

// ---------------- threefry2x32 (JAX-exact) ----------------
__host__ __device__ inline void threefry2x32(uint32_t k0, uint32_t k1,
                                             uint32_t x0, uint32_t x1,
                                             uint32_t& o0, uint32_t& o1) {
  uint32_t ks2 = k0 ^ k1 ^ 0x1BD11BDAu;
#define TF_ROT(x, r) (((x) << (r)) | ((x) >> (32 - (r))))
#define TF_RND(r) { x0 += x1; x1 = TF_ROT(x1, r); x1 ^= x0; }
  x0 += k0; x1 += k1;
  TF_RND(13) TF_RND(15) TF_RND(26) TF_RND(6)
  x0 += k1; x1 += ks2 + 1u;
  TF_RND(17) TF_RND(29) TF_RND(16) TF_RND(24)
  x0 += ks2; x1 += k0 + 2u;
  TF_RND(13) TF_RND(15) TF_RND(26) TF_RND(6)
  x0 += k0; x1 += k1 + 3u;
  TF_RND(17) TF_RND(29) TF_RND(16) TF_RND(24)
  x0 += k1; x1 += ks2 + 4u;
  TF_RND(13) TF_RND(15) TF_RND(26) TF_RND(6)
  x0 += ks2; x1 += k0 + 5u;
  o0 = x0; o1 = x1;
#undef TF_RND
#undef TF_ROT
}

__device__ __forceinline__ uint32_t rb32(uint32_t k0, uint32_t k1, uint32_t idx) {
  uint32_t a, b;
  threefry2x32(k0, k1, 0u, idx, a, b);
  return a ^ b;
}

__device__ __forceinline__ float u01_from_bits(uint32_t bits) {
  return __uint_as_float((bits >> 9) | 0x3f800000u) - 1.0f;  // [0,1)
}

// XLA ErfInv32 (Giles single-precision polynomial)
__device__ __forceinline__ float erfinv_f32(float x) {
  float w = -log1pf(-x * x);
  float p;
  if (w < 5.0f) {
    w = w - 2.5f;
    p = 2.81022636e-08f;
    p = fmaf(p, w, 3.43273939e-07f);
    p = fmaf(p, w, -3.5233877e-06f);
    p = fmaf(p, w, -4.39150654e-06f);
    p = fmaf(p, w, 0.00021858087f);
    p = fmaf(p, w, -0.00125372503f);
    p = fmaf(p, w, -0.00417768164f);
    p = fmaf(p, w, 0.246640727f);
    p = fmaf(p, w, 1.50140941f);
  } else {
    w = sqrtf(w) - 3.0f;
    p = -0.000200214257f;
    p = fmaf(p, w, 0.000100950558f);
    p = fmaf(p, w, 0.00134934322f);
    p = fmaf(p, w, -0.00367342844f);
    p = fmaf(p, w, 0.00573950773f);
    p = fmaf(p, w, -0.0076224613f);
    p = fmaf(p, w, 0.00943887047f);
    p = fmaf(p, w, 1.00167406f);
    p = fmaf(p, w, 2.83297682f);
  }
  return p * x;
}

// ---------------- bf16 split helpers (R2-verified) ----------------
__device__ __forceinline__ unsigned short bf16_rne(float x) {
  uint32_t u = __float_as_uint(x);
  uint32_t r = u + 0x7fffu + ((u >> 16) & 1u);
  return (unsigned short)(r >> 16);
}

__device__ __forceinline__ void split2(float x, short& hi, short& lo) {
  unsigned short hb = bf16_rne(x);
  float hf = __uint_as_float((uint32_t)hb << 16);
  hi = (short)hb;
  lo = (short)bf16_rne(x - hf);
}

// ---------------- async global->LDS (16B/lane) ----------------
__device__ __forceinline__ void gload16(const void* g, void* l) {
  __builtin_amdgcn_global_load_lds(
      (const __attribute__((address_space(1))) void*)g,
      (__attribute__((address_space(3))) void*)l, 16, 0, 0);
}

// stage ROWS x 32 bf16 tile (row-major, 64B rows) from global [rows][512]
template <int ROWS>
__device__ __forceinline__ void stage_region(const short* __restrict__ g,
                                             short* l, int wid, int lane) {
#pragma unroll
  for (int c = wid; c < ROWS / 16; c += 4) {
    const short* gp = g + (size_t)(c * 16 + (lane >> 2)) * 512 + (lane & 3) * 8;
    gload16(gp, l + c * 512);
  }
}

// ---------------- prep: xcat = [x*mask, mask]  (bit-identical to R1) ------
__global__ __launch_bounds__(256) void prep_kernel(const float* __restrict__ x,
                                                   const float* __restrict__ mask,
                                                   float* __restrict__ xcat) {
  int i = blockIdx.x * 256 + threadIdx.x;  // over B*512
  if (i >= B * 2 * D) return;
  int b = i >> 9, c = i & 511;
  float v = (c < D) ? x[b * D + c] * mask[b * D + c] : mask[b * D + (c - D)];
  xcat[i] = v;
}

// ---------------- logit weight gather: wsgL[k][c] = Wf[k][(c/10)*94 + c%10]
__global__ __launch_bounds__(256) void wgatherL(const float* __restrict__ Wf,
                                                float* __restrict__ wsgL) {
  int c = blockIdx.x * 256 + threadIdx.x;  // 0..2559
  int k = blockIdx.y;                      // 0..511
  int dd = c / K, j = c - dd * K;
  wsgL[(size_t)k * NLOG + c] = Wf[(size_t)k * (D * HEADW) + dd * HEADW + j];
}

// ---- MS weight transpose + 2-split: Wf[512][24064] -> wms hi/lo [5120][512]
__global__ __launch_bounds__(256) void wsplit_ms(const float* __restrict__ Wf,
                                                 short* __restrict__ whi,
                                                 short* __restrict__ wlo) {
  __shared__ float tile[32][33];
  int n0 = blockIdx.x * 32, k0 = blockIdx.y * 32;
  int tx = threadIdx.x & 31, ty = threadIdx.x >> 5;  // 32 x 8
#pragma unroll
  for (int r = 0; r < 4; ++r) {
    int k = k0 + ty + r * 8;
    int n = n0 + tx;
    int dd = n / 20, j = n - dd * 20;
    tile[ty + r * 8][tx] = Wf[(size_t)k * (D * HEADW) + dd * HEADW + 10 + j];
  }
  __syncthreads();
#pragma unroll
  for (int r = 0; r < 4; ++r) {
    int n = n0 + ty + r * 8;
    int k = k0 + tx;
    float v = tile[tx][ty + r * 8];
    short hb, lb;
    split2(v, hb, lb);
    whi[(size_t)n * 512 + k] = hb;
    wlo[(size_t)n * 512 + k] = lb;
  }
}

// ---------------- fp32 trunk GEMM (bit-identical chains to R1) ----------
// C(4096x512) = [relu?](A) @ W(512x512) + bias [+ res]
// 128x64 tile, BK=32, 256 threads, 8x4/thread. A via LDS transpose;
// B streamed from global (L2) in double-buffered 8-kk register chunks.
// Per-output: ONE sequential fmaf chain over ascending k -> bit-identical.
template <int RELU, int RES>
__global__ __launch_bounds__(256) void gemm_trunk(const float* __restrict__ A,
                                                  const float* __restrict__ W,
                                                  const float* __restrict__ bias,
                                                  const float* res, float* C) {
  __shared__ float As[32 * 136];  // [k][m], stride 136
  const int tid = threadIdx.x;
  const int tx = tid & 15, ty = tid >> 4;
  const int bm = blockIdx.y * 128, bn = blockIdx.x * 64;
  const int ls = tid & 7, lm = tid >> 3;  // A-load: k-slot, row

  const float* Wp = W + bn + tx * 4;  // this thread's 4 columns
  float acc[8][4] = {};

  for (int k0 = 0; k0 < H; k0 += 32) {
    float4 bb[2][8];
    // first B chunk (kk 0..7) issued before the staging barrier
#pragma unroll
    for (int j = 0; j < 8; ++j) bb[0][j] = *(const float4*)(Wp + (size_t)(k0 + j) * H);
    // A: load float4 along k, transpose into [k][m]
#pragma unroll
    for (int r = 0; r < 4; ++r) {
      int m = lm + 32 * r;
      float4 f = *(const float4*)(A + (size_t)(bm + m) * H + k0 + 4 * ls);
      if (RELU) {
        f.x = fmaxf(f.x, 0.0f); f.y = fmaxf(f.y, 0.0f);
        f.z = fmaxf(f.z, 0.0f); f.w = fmaxf(f.w, 0.0f);
      }
      As[(4 * ls + 0) * 136 + m] = f.x;
      As[(4 * ls + 1) * 136 + m] = f.y;
      As[(4 * ls + 2) * 136 + m] = f.z;
      As[(4 * ls + 3) * 136 + m] = f.w;
    }
    __syncthreads();
#pragma unroll
    for (int c = 0; c < 4; ++c) {
      const int cb = c & 1;
      if (c < 3) {
#pragma unroll
        for (int j = 0; j < 8; ++j)
          bb[cb ^ 1][j] = *(const float4*)(Wp + (size_t)(k0 + c * 8 + 8 + j) * H);
      }
#pragma unroll
      for (int j = 0; j < 8; ++j) {
        int kk = c * 8 + j;
        float a[8];
        *(float4*)(a + 0) = *(const float4*)(As + kk * 136 + ty * 8);
        *(float4*)(a + 4) = *(const float4*)(As + kk * 136 + ty * 8 + 4);
        float b[4] = {bb[cb][j].x, bb[cb][j].y, bb[cb][j].z, bb[cb][j].w};
#pragma unroll
        for (int i = 0; i < 8; ++i)
#pragma unroll
          for (int jj = 0; jj < 4; ++jj) acc[i][jj] = fmaf(a[i], b[jj], acc[i][jj]);
      }
    }
    __syncthreads();
  }
#pragma unroll
  for (int i = 0; i < 8; ++i) {
    int row = bm + ty * 8 + i;
#pragma unroll
    for (int j = 0; j < 4; ++j) {
      int col = bn + tx * 4 + j;
      float v = acc[i][j] + bias[col];
      if (RES) v = res[(size_t)row * H + col] + v;  // same order as R1
      C[(size_t)row * H + col] = v;
    }
  }
}

// ---------------- fp32 fin-LOGITS GEMM (bit-identical chains) ----------
// head logits (4096 x 2560) = h @ wsgL + bf(logit cols); no softplus.
// 128x128 tile, BK=32, 8x8/thread. A via LDS; B global double-buffered
// in 4-kk chunks (8 float4 per buffer).
__global__ __launch_bounds__(256) void gemm_logits(const float* __restrict__ A,
                                                   const float* __restrict__ Wg,
                                                   const float* __restrict__ bf,
                                                   float* __restrict__ headout) {
  __shared__ float As[32 * 136];  // [k][m]
  const int tid = threadIdx.x;
  const int tx = tid & 15, ty = tid >> 4;
  const int bm = blockIdx.y * 128, bn = blockIdx.x * 128;
  const int ls = tid & 7, lm = tid >> 3;

  const float* Wp = Wg + bn + tx * 8;  // this thread's 8 columns
  float acc[8][8] = {};

  for (int k0 = 0; k0 < H; k0 += 32) {
    float4 bb[2][8];
#pragma unroll
    for (int j = 0; j < 4; ++j) {
      bb[0][2 * j]     = *(const float4*)(Wp + (size_t)(k0 + j) * NLOG);
      bb[0][2 * j + 1] = *(const float4*)(Wp + (size_t)(k0 + j) * NLOG + 4);
    }
#pragma unroll
    for (int r = 0; r < 4; ++r) {
      int m = lm + 32 * r;
      float4 f = *(const float4*)(A + (size_t)(bm + m) * H + k0 + 4 * ls);
      As[(4 * ls + 0) * 136 + m] = f.x;
      As[(4 * ls + 1) * 136 + m] = f.y;
      As[(4 * ls + 2) * 136 + m] = f.z;
      As[(4 * ls + 3) * 136 + m] = f.w;
    }
    __syncthreads();
#pragma unroll
    for (int c = 0; c < 8; ++c) {
      const int cb = c & 1;
      if (c < 7) {
#pragma unroll
        for (int j = 0; j < 4; ++j) {
          bb[cb ^ 1][2 * j]     = *(const float4*)(Wp + (size_t)(k0 + c * 4 + 4 + j) * NLOG);
          bb[cb ^ 1][2 * j + 1] = *(const float4*)(Wp + (size_t)(k0 + c * 4 + 4 + j) * NLOG + 4);
        }
      }
#pragma unroll
      for (int j = 0; j < 4; ++j) {
        int kk = c * 4 + j;
        float a[8], b[8];
        *(float4*)(a + 0) = *(const float4*)(As + kk * 136 + ty * 8);
        *(float4*)(a + 4) = *(const float4*)(As + kk * 136 + ty * 8 + 4);
        *(float4*)(b + 0) = bb[cb][2 * j];
        *(float4*)(b + 4) = bb[cb][2 * j + 1];
#pragma unroll
        for (int i = 0; i < 8; ++i)
#pragma unroll
          for (int jj = 0; jj < 8; ++jj) acc[i][jj] = fmaf(a[i], b[jj], acc[i][jj]);
      }
    }
    __syncthreads();
  }
#pragma unroll
  for (int i = 0; i < 8; ++i) {
    int row = bm + ty * 8 + i;
#pragma unroll
    for (int j = 0; j < 8; ++j) {
      int c = bn + tx * 8 + j;           // 0..2559 logit col
      int dd = c / K, jj = c - dd * K;
      float v = acc[i][j] + bf[dd * HEADW + jj];
      headout[(size_t)row * NFIN + dd * NOUT + jj] = v;
    }
  }
}

// ---------------- MS MFMA GEMM (R2/R5-verified fragment/epilogue) --------
__global__ __launch_bounds__(256) void gemm_ms(const float* __restrict__ A,
                                               const short* __restrict__ Bh,
                                               const short* __restrict__ Bl,
                                               const float* __restrict__ bf,
                                               float* __restrict__ headout) {
  __shared__ short lds[4 * 128 * 32];  // Ah, Al, Bh, Bl (8 KB each)
  const int tid = threadIdx.x;
  const int lane = tid & 63, wid = tid >> 6;
  const int wm = wid >> 1, wn = wid & 1;
  const int bm = blockIdx.y * 128, bn = blockIdx.x * 128;
  const int ls = tid & 7, lm = tid >> 3;

  short* ldsAh = lds;
  short* ldsAl = lds + 4096;
  short* ldsBh = lds + 8192;
  short* ldsBl = lds + 12288;

  const short* gBh = Bh + (size_t)bn * 512;
  const short* gBl = Bl + (size_t)bn * 512;

  f32x16 acc[2][2];
#pragma unroll
  for (int mt = 0; mt < 2; ++mt)
#pragma unroll
    for (int nt = 0; nt < 2; ++nt)
#pragma unroll
      for (int i = 0; i < 16; ++i) acc[mt][nt][i] = 0.0f;

  for (int k0 = 0; k0 < 512; k0 += 32) {
    stage_region<128>(gBh + k0, ldsBh, wid, lane);
    stage_region<128>(gBl + k0, ldsBl, wid, lane);
#pragma unroll
    for (int r = 0; r < 4; ++r) {
      int m = lm + 32 * r;
      float4 f = *(const float4*)(A + (size_t)(bm + m) * H + k0 + 4 * ls);
      short4 h4, l4;
      split2(f.x, h4.x, l4.x); split2(f.y, h4.y, l4.y);
      split2(f.z, h4.z, l4.z); split2(f.w, h4.w, l4.w);
      *(short4*)(ldsAh + m * 32 + 4 * ls) = h4;
      *(short4*)(ldsAl + m * 32 + 4 * ls) = l4;
    }
    __syncthreads();
#pragma unroll
    for (int sub = 0; sub < 2; ++sub) {
      bf16x8 ah[2], al[2], bh[2], bl[2];
#pragma unroll
      for (int mt = 0; mt < 2; ++mt) {
        int r = wm * 64 + mt * 32 + (lane & 31);
        int off = r * 32 + sub * 16 + (lane >> 5) * 8;
        ah[mt] = *(const bf16x8*)(ldsAh + off);
        al[mt] = *(const bf16x8*)(ldsAl + off);
      }
#pragma unroll
      for (int nt = 0; nt < 2; ++nt) {
        int r = wn * 64 + nt * 32 + (lane & 31);
        int off = r * 32 + sub * 16 + (lane >> 5) * 8;
        bh[nt] = *(const bf16x8*)(ldsBh + off);
        bl[nt] = *(const bf16x8*)(ldsBl + off);
      }
#pragma unroll
      for (int mt = 0; mt < 2; ++mt)
#pragma unroll
        for (int nt = 0; nt < 2; ++nt) {
          acc[mt][nt] = __builtin_amdgcn_mfma_f32_32x32x16_bf16(ah[mt], bh[nt], acc[mt][nt], 0, 0, 0);
          acc[mt][nt] = __builtin_amdgcn_mfma_f32_32x32x16_bf16(ah[mt], bl[nt], acc[mt][nt], 0, 0, 0);
          acc[mt][nt] = __builtin_amdgcn_mfma_f32_32x32x16_bf16(al[mt], bh[nt], acc[mt][nt], 0, 0, 0);
        }
    }
    __syncthreads();
  }

#pragma unroll
  for (int mt = 0; mt < 2; ++mt)
#pragma unroll
    for (int nt = 0; nt < 2; ++nt) {
      int col = bn + wn * 64 + nt * 32 + (lane & 31);   // 0..5119
      int rbase = bm + wm * 64 + mt * 32 + 4 * (lane >> 5);
      int dd = col / 20, j = col - dd * 20;
#pragma unroll
      for (int reg = 0; reg < 16; ++reg) {
        int row = rbase + (reg & 3) + 8 * (reg >> 2);
        float v = acc[mt][nt][reg] + bf[dd * HEADW + 10 + j];
        if (j >= 10) v = (fmaxf(v, 0.0f) + log1pf(expf(-fabsf(v)))) + 0.001f;
        headout[(size_t)row * NFIN + dd * NOUT + 10 + j] = v;
      }
    }
}

// ---------------- fused tail: ll + mean + samples ------------------------
// ll/mean/eps arithmetic verbatim R5 (bit-identical). Categorical selection
// via monotone transform: argmax_k(g_k + l_k) == argmin_k (-log2(u_k))/e_k
// (ln2 and exp(-m) scale factors drop inside argmin/argmax).
__global__ __launch_bounds__(256) void fused_tail(const float* __restrict__ head,
                                                  const float* __restrict__ x,
                                                  const float* __restrict__ mask,
                                                  float* __restrict__ out_ll,
                                                  float* __restrict__ out_s,
                                                  float* __restrict__ out_mean,
                                                  uint32_t kc0, uint32_t kc1,
                                                  uint32_t kn0, uint32_t kn1) {
  int idx = blockIdx.x * 256 + threadIdx.x;  // b*D + d
  if (idx >= ND) return;
  int b = idx >> 8, d = idx & (D - 1);
  const float* hp = head + (size_t)idx * NOUT;
  float lg[K], mn[K], sc[K];
#pragma unroll
  for (int k = 0; k < K; ++k) { lg[k] = hp[k]; mn[k] = hp[K + k]; sc[k] = hp[2 * K + k]; }
  float q = 1.0f - mask[idx];
  float xu = x[idx] * q;
  // ---- ll + mean (verbatim R5) ----
  float m = lg[0];
#pragma unroll
  for (int k = 1; k < K; ++k) m = fmaxf(m, lg[k]);
  float e[K];
  float sum = 0.0f;
#pragma unroll
  for (int k = 0; k < K; ++k) { e[k] = expf(lg[k] - m); sum += e[k]; }
  float lse = logf(sum);
  float a[K];
  float amax = -3.402823466e38f;
#pragma unroll
  for (int k = 0; k < K; ++k) {
    float z = (xu - mn[k]) / sc[k];
    float cll = -0.5f * z * z - logf(sc[k]) - 0.9189385332046727f;
    float lw = (lg[k] - m) - lse;
    a[k] = lw + cll;
    amax = fmaxf(amax, a[k]);
  }
  float s2 = 0.0f;
#pragma unroll
  for (int k = 0; k < K; ++k) s2 += expf(a[k] - amax);
  out_ll[idx] = (logf(s2) + amax) * q;
  float pm = 0.0f;
#pragma unroll
  for (int k = 0; k < K; ++k) pm += (e[k] / sum) * mn[k];
  out_mean[idx] = pm * q;
  // ---- samples: transformed categorical + exact eps ----
  float inv_e[K];
#pragma unroll
  for (int k = 0; k < K; ++k) inv_e[k] = 1.0f / e[k];
  for (int s = 0; s < S; ++s) {
    uint32_t t32 = (uint32_t)s * (uint32_t)ND + (uint32_t)idx;
    uint32_t base = t32 * (uint32_t)K;
    int best = 0;
    float rbest = 3.402823466e38f;
#pragma unroll
    for (int k = 0; k < K; ++k) {
      uint32_t bits = rb32(kc0, kc1, base + (uint32_t)k);
      float u = u01_from_bits(bits);
      float wv = -__log2f(u);              // hw v_log_f32; u=0 -> +inf (never wins)
      float r = wv * inv_e[k];
      if (r < rbest) { rbest = r; best = k; }  // first-min == reference first-max
    }
    uint32_t ebits = rb32(kn0, kn1, t32);
    float f = u01_from_bits(ebits);
    float r2 = f * 2.0f + (-0.99999994f);
    r2 = fmaxf(r2, -0.99999994f);
    float eps = 1.4142135623730951f * erfinv_f32(r2);
    out_s[((size_t)b * S + s) * D + d] = (mn[best] + sc[best] * eps) * q;
  }
}

// ---------------- launch ----------------
extern "C" void kernel_launch(void* const* d_in, const int* in_sizes, int n_in,
                              void* d_out, int out_size, void* d_ws, size_t ws_size,
                              hipStream_t stream) {
  const float* x    = (const float*)d_in[0];
  const float* mask = (const float*)d_in[1];
  const float* W_in = (const float*)d_in[2];
  const float* b_in = (const float*)d_in[3];
  const float* W1   = (const float*)d_in[4];
  const float* b1   = (const float*)d_in[5];
  const float* W2   = (const float*)d_in[6];
  const float* b2   = (const float*)d_in[7];
  const float* Wf   = (const float*)d_in[8];
  const float* bf   = (const float*)d_in[9];

  // workspace: head 125,829,120 + h 8,388,608 + wsgL 5,242,880
  //          + wms_h 5,242,880 + wms_l 5,242,880 = 149,946,368 B (fits cap)
  char* w = (char*)d_ws;
  float* head  = (float*)w;                     // B*7680 f32
  float* xcat  = head;                          // alias: dead after gemm0
  float* t     = head;                          // alias: dead before fin
  float* h     = (float*)(w + 125829120);       // B*512 f32 (live through fin)
  float* wsgL  = (float*)(w + 134217728);       // 512*2560 f32 logit weights
  short* wms_h = (short*)(w + 139460608);       // 5120*512 bf16
  short* wms_l = (short*)(w + 144703488);       // 5120*512 bf16

  float* out_ll   = (float*)d_out;              // (B,D)
  float* out_s    = out_ll + (size_t)ND;        // (B,S,D)
  float* out_mean = out_s + (size_t)ND * S;     // (B,D)

  wgatherL<<<dim3(NLOG / 256, 512), 256, 0, stream>>>(Wf, wsgL);
  wsplit_ms<<<dim3(NMS / 32, 512 / 32), 256, 0, stream>>>(Wf, wms_h, wms_l);

  prep_kernel<<<(B * 2 * D) / 256, 256, 0, stream>>>(x, mask, xcat);

  dim3 gtr(H / 64, B / 128);  // (8, 32) = 256 blocks
  gemm_trunk<0, 0><<<gtr, 256, 0, stream>>>(xcat, W_in, b_in, nullptr, h);
  for (int l = 0; l < NL; ++l) {
    gemm_trunk<1, 0><<<gtr, 256, 0, stream>>>(h, W1 + (size_t)l * H * H,
                                              b1 + (size_t)l * H, nullptr, t);
    gemm_trunk<1, 1><<<gtr, 256, 0, stream>>>(t, W2 + (size_t)l * H * H,
                                              b2 + (size_t)l * H, h, h);
  }

  gemm_logits<<<dim3(NLOG / 128, B / 128), 256, 0, stream>>>(h, wsgL, bf, head);
  gemm_ms<<<dim3(NMS / 128, B / 128), 256, 0, stream>>>(h, wms_h, wms_l, bf, head);

  uint32_t kc0, kc1, kn0, kn1;
  threefry2x32(0u, 1234u, 0u, 0u, kc0, kc1);
  threefry2x32(0u, 1234u, 0u, 1u, kn0, kn1);
  fused_tail<<<ND / 256, 256, 0, stream>>>(head, x, mask, out_ll, out_s, out_mean,
                                           kc0, kc1, kn0, kn1);
}

// Round 7
// 1369.392 us; speedup vs baseline: 1.0348x; 1.0348x over previous
//
#include <hip/hip_runtime.h>
#include <cstdint>

#define B 4096
#define D 256
#define H 512
#define K 10
#define NL 4
#define S 10
#define NOUT 30           // used head columns per d (3*K); tail C=64 unused
#define HEADW 94          // 3*K + C
#define ND (B*D)          // 1048576
#define NFIN 7680         // D*NOUT
#define NLOG 2560         // D*K   logits columns (exact fp32)
#define NMS  5120         // D*2K  means+scales columns (MFMA path)

typedef __bf16 bf16x8 __attribute__((ext_vector_type(8)));
typedef float  f32x16 __attribute__((ext_vector_type(16)));

// ---------------- threefry2x32 (JAX-exact) ----------------
__host__ __device__ inline void threefry2x32(uint32_t k0, uint32_t k1,
                                             uint32_t x0, uint32_t x1,
                                             uint32_t& o0, uint32_t& o1) {
  uint32_t ks2 = k0 ^ k1 ^ 0x1BD11BDAu;
#define TF_ROT(x, r) (((x) << (r)) | ((x) >> (32 - (r))))
#define TF_RND(r) { x0 += x1; x1 = TF_ROT(x1, r); x1 ^= x0; }
  x0 += k0; x1 += k1;
  TF_RND(13) TF_RND(15) TF_RND(26) TF_RND(6)
  x0 += k1; x1 += ks2 + 1u;
  TF_RND(17) TF_RND(29) TF_RND(16) TF_RND(24)
  x0 += ks2; x1 += k0 + 2u;
  TF_RND(13) TF_RND(15) TF_RND(26) TF_RND(6)
  x0 += k0; x1 += k1 + 3u;
  TF_RND(17) TF_RND(29) TF_RND(16) TF_RND(24)
  x0 += k1; x1 += ks2 + 4u;
  TF_RND(13) TF_RND(15) TF_RND(26) TF_RND(6)
  x0 += ks2; x1 += k0 + 5u;
  o0 = x0; o1 = x1;
#undef TF_RND
#undef TF_ROT
}

__device__ __forceinline__ uint32_t rb32(uint32_t k0, uint32_t k1, uint32_t idx) {
  uint32_t a, b;
  threefry2x32(k0, k1, 0u, idx, a, b);
  return a ^ b;
}

__device__ __forceinline__ float u01_from_bits(uint32_t bits) {
  return __uint_as_float((bits >> 9) | 0x3f800000u) - 1.0f;  // [0,1)
}

// XLA ErfInv32 (Giles single-precision polynomial)
__device__ __forceinline__ float erfinv_f32(float x) {
  float w = -log1pf(-x * x);
  float p;
  if (w < 5.0f) {
    w = w - 2.5f;
    p = 2.81022636e-08f;
    p = fmaf(p, w, 3.43273939e-07f);
    p = fmaf(p, w, -3.5233877e-06f);
    p = fmaf(p, w, -4.39150654e-06f);
    p = fmaf(p, w, 0.00021858087f);
    p = fmaf(p, w, -0.00125372503f);
    p = fmaf(p, w, -0.00417768164f);
    p = fmaf(p, w, 0.246640727f);
    p = fmaf(p, w, 1.50140941f);
  } else {
    w = sqrtf(w) - 3.0f;
    p = -0.000200214257f;
    p = fmaf(p, w, 0.000100950558f);
    p = fmaf(p, w, 0.00134934322f);
    p = fmaf(p, w, -0.00367342844f);
    p = fmaf(p, w, 0.00573950773f);
    p = fmaf(p, w, -0.0076224613f);
    p = fmaf(p, w, 0.00943887047f);
    p = fmaf(p, w, 1.00167406f);
    p = fmaf(p, w, 2.83297682f);
  }
  return p * x;
}

// ---------------- bf16 split helpers (R2-verified) ----------------
__device__ __forceinline__ unsigned short bf16_rne(float x) {
  uint32_t u = __float_as_uint(x);
  uint32_t r = u + 0x7fffu + ((u >> 16) & 1u);
  return (unsigned short)(r >> 16);
}

__device__ __forceinline__ void split2(float x, short& hi, short& lo) {
  unsigned short hb = bf16_rne(x);
  float hf = __uint_as_float((uint32_t)hb << 16);
  hi = (short)hb;
  lo = (short)bf16_rne(x - hf);
}

// ---------------- async global->LDS (16B/lane) ----------------
__device__ __forceinline__ void gload16(const void* g, void* l) {
  __builtin_amdgcn_global_load_lds(
      (const __attribute__((address_space(1))) void*)g,
      (__attribute__((address_space(3))) void*)l, 16, 0, 0);
}

// stage ROWS x 32 bf16 tile (row-major, 64B rows) from global [rows][512]
template <int ROWS>
__device__ __forceinline__ void stage_region(const short* __restrict__ g,
                                             short* l, int wid, int lane) {
#pragma unroll
  for (int c = wid; c < ROWS / 16; c += 4) {
    const short* gp = g + (size_t)(c * 16 + (lane >> 2)) * 512 + (lane & 3) * 8;
    gload16(gp, l + c * 512);
  }
}

// ---------------- prep: xcat = [x*mask, mask]  (bit-identical to R1) ------
__global__ __launch_bounds__(256) void prep_kernel(const float* __restrict__ x,
                                                   const float* __restrict__ mask,
                                                   float* __restrict__ xcat) {
  int i = blockIdx.x * 256 + threadIdx.x;  // over B*512
  if (i >= B * 2 * D) return;
  int b = i >> 9, c = i & 511;
  float v = (c < D) ? x[b * D + c] * mask[b * D + c] : mask[b * D + (c - D)];
  xcat[i] = v;
}

// ---------------- logit weight gather: wsgL[k][c] = Wf[k][(c/10)*94 + c%10]
__global__ __launch_bounds__(256) void wgatherL(const float* __restrict__ Wf,
                                                float* __restrict__ wsgL) {
  int c = blockIdx.x * 256 + threadIdx.x;  // 0..2559
  int k = blockIdx.y;                      // 0..511
  int dd = c / K, j = c - dd * K;
  wsgL[(size_t)k * NLOG + c] = Wf[(size_t)k * (D * HEADW) + dd * HEADW + j];
}

// ---- MS weight transpose + 2-split: Wf[512][24064] -> wms hi/lo [5120][512]
__global__ __launch_bounds__(256) void wsplit_ms(const float* __restrict__ Wf,
                                                 short* __restrict__ whi,
                                                 short* __restrict__ wlo) {
  __shared__ float tile[32][33];
  int n0 = blockIdx.x * 32, k0 = blockIdx.y * 32;
  int tx = threadIdx.x & 31, ty = threadIdx.x >> 5;  // 32 x 8
#pragma unroll
  for (int r = 0; r < 4; ++r) {
    int k = k0 + ty + r * 8;
    int n = n0 + tx;
    int dd = n / 20, j = n - dd * 20;
    tile[ty + r * 8][tx] = Wf[(size_t)k * (D * HEADW) + dd * HEADW + 10 + j];
  }
  __syncthreads();
#pragma unroll
  for (int r = 0; r < 4; ++r) {
    int n = n0 + ty + r * 8;
    int k = k0 + tx;
    float v = tile[tx][ty + r * 8];
    short hb, lb;
    split2(v, hb, lb);
    whi[(size_t)n * 512 + k] = hb;
    wlo[(size_t)n * 512 + k] = lb;
  }
}

// ---------------- fp32 trunk GEMM (bit-identical chains to R1) ----------
// C(4096x512) = [relu?](A) @ W(512x512) + bias [+ res]
// 64x64 tile, 128 threads (2 waves), BK=32, 8x4 acc. 512 blocks = 2/CU so
// barrier stalls overlap across blocks. Per-output: ONE sequential fmaf
// chain over ascending k -> bit-identical to R1/R4.
template <int RELU, int RES>
__global__ __launch_bounds__(128) void gemm_trunk(const float* __restrict__ A,
                                                  const float* __restrict__ W,
                                                  const float* __restrict__ bias,
                                                  const float* res, float* C) {
  __shared__ float As[32 * 68];  // [k][m], stride 68 (272B, 16B-aligned)
  __shared__ float Ws[32 * 64];  // [k][n], stride 64
  const int tid = threadIdx.x;
  const int lane = tid & 63, wid = tid >> 6;  // 2 waves
  const int tx = tid & 15, ty = tid >> 4;     // 16 x 8
  const int bm = blockIdx.y * 64, bn = blockIdx.x * 64;
  const int ls = tid & 7, lm = tid >> 3;      // A-load: k-slot, row (0..15)

  float acc[8][4] = {};

  for (int k0 = 0; k0 < H; k0 += 32) {
    // B: direct global->LDS, [k][n]; 2 waves cover 8 chunks of 4 rows
#pragma unroll
    for (int c = wid; c < 8; c += 2) {
      gload16(W + (size_t)(k0 + c * 4 + (lane >> 4)) * H + bn + (lane & 15) * 4,
              Ws + c * 256 + lane * 4);
    }
    // A: load float4 along k, transpose into [k][m]
#pragma unroll
    for (int r = 0; r < 4; ++r) {
      int m = lm + 16 * r;
      float4 f = *(const float4*)(A + (size_t)(bm + m) * H + k0 + 4 * ls);
      if (RELU) {
        f.x = fmaxf(f.x, 0.0f); f.y = fmaxf(f.y, 0.0f);
        f.z = fmaxf(f.z, 0.0f); f.w = fmaxf(f.w, 0.0f);
      }
      As[(4 * ls + 0) * 68 + m] = f.x;
      As[(4 * ls + 1) * 68 + m] = f.y;
      As[(4 * ls + 2) * 68 + m] = f.z;
      As[(4 * ls + 3) * 68 + m] = f.w;
    }
    __syncthreads();
#pragma unroll
    for (int kk = 0; kk < 32; ++kk) {
      float a[8], b[4];
      *(float4*)(a + 0) = *(const float4*)(As + kk * 68 + ty * 8);
      *(float4*)(a + 4) = *(const float4*)(As + kk * 68 + ty * 8 + 4);
      *(float4*)(b + 0) = *(const float4*)(Ws + kk * 64 + tx * 4);
#pragma unroll
      for (int i = 0; i < 8; ++i)
#pragma unroll
        for (int j = 0; j < 4; ++j) acc[i][j] = fmaf(a[i], b[j], acc[i][j]);
    }
    __syncthreads();
  }
#pragma unroll
  for (int i = 0; i < 8; ++i) {
    int row = bm + ty * 8 + i;
#pragma unroll
    for (int j = 0; j < 4; ++j) {
      int col = bn + tx * 4 + j;
      float v = acc[i][j] + bias[col];
      if (RES) v = res[(size_t)row * H + col] + v;  // same order as R1
      C[(size_t)row * H + col] = v;
    }
  }
}

// ---------------- fp32 fin-LOGITS GEMM (R5-proven, bit-identical) --------
// head logits (4096 x 2560) = h @ wsgL + bf(logit cols); no softplus.
// 128x128 tile, BK=32, 256 threads, 8x8/thread, A+B in LDS.
__global__ __launch_bounds__(256) void gemm_logits(const float* __restrict__ A,
                                                   const float* __restrict__ Wg,
                                                   const float* __restrict__ bf,
                                                   float* __restrict__ headout) {
  __shared__ float As[32 * 136];  // [k][m]
  __shared__ float Ws[32 * 128];  // [k][n]
  const int tid = threadIdx.x;
  const int lane = tid & 63, wid = tid >> 6;
  const int tx = tid & 15, ty = tid >> 4;
  const int bm = blockIdx.y * 128, bn = blockIdx.x * 128;
  const int ls = tid & 7, lm = tid >> 3;

  float acc[8][8] = {};

  for (int k0 = 0; k0 < H; k0 += 32) {
#pragma unroll
    for (int c = wid; c < 16; c += 4) {
      gload16(Wg + (size_t)(k0 + c * 2 + (lane >> 5)) * NLOG + bn + (lane & 31) * 4,
              Ws + c * 256 + lane * 4);
    }
#pragma unroll
    for (int r = 0; r < 4; ++r) {
      int m = lm + 32 * r;
      float4 f = *(const float4*)(A + (size_t)(bm + m) * H + k0 + 4 * ls);
      As[(4 * ls + 0) * 136 + m] = f.x;
      As[(4 * ls + 1) * 136 + m] = f.y;
      As[(4 * ls + 2) * 136 + m] = f.z;
      As[(4 * ls + 3) * 136 + m] = f.w;
    }
    __syncthreads();
#pragma unroll
    for (int kk = 0; kk < 32; ++kk) {
      float a[8], b[8];
      *(float4*)(a + 0) = *(const float4*)(As + kk * 136 + ty * 8);
      *(float4*)(a + 4) = *(const float4*)(As + kk * 136 + ty * 8 + 4);
      *(float4*)(b + 0) = *(const float4*)(Ws + kk * 128 + tx * 8);
      *(float4*)(b + 4) = *(const float4*)(Ws + kk * 128 + tx * 8 + 4);
#pragma unroll
      for (int i = 0; i < 8; ++i)
#pragma unroll
        for (int j = 0; j < 8; ++j) acc[i][j] = fmaf(a[i], b[j], acc[i][j]);
    }
    __syncthreads();
  }
#pragma unroll
  for (int i = 0; i < 8; ++i) {
    int row = bm + ty * 8 + i;
#pragma unroll
    for (int j = 0; j < 8; ++j) {
      int c = bn + tx * 8 + j;           // 0..2559 logit col
      int dd = c / K, jj = c - dd * K;
      float v = acc[i][j] + bf[dd * HEADW + jj];
      headout[(size_t)row * NFIN + dd * NOUT + jj] = v;
    }
  }
}

// ---------------- MS MFMA GEMM (R2/R5-verified fragment/epilogue) --------
__global__ __launch_bounds__(256) void gemm_ms(const float* __restrict__ A,
                                               const short* __restrict__ Bh,
                                               const short* __restrict__ Bl,
                                               const float* __restrict__ bf,
                                               float* __restrict__ headout) {
  __shared__ short lds[4 * 128 * 32];  // Ah, Al, Bh, Bl (8 KB each)
  const int tid = threadIdx.x;
  const int lane = tid & 63, wid = tid >> 6;
  const int wm = wid >> 1, wn = wid & 1;
  const int bm = blockIdx.y * 128, bn = blockIdx.x * 128;
  const int ls = tid & 7, lm = tid >> 3;

  short* ldsAh = lds;
  short* ldsAl = lds + 4096;
  short* ldsBh = lds + 8192;
  short* ldsBl = lds + 12288;

  const short* gBh = Bh + (size_t)bn * 512;
  const short* gBl = Bl + (size_t)bn * 512;

  f32x16 acc[2][2];
#pragma unroll
  for (int mt = 0; mt < 2; ++mt)
#pragma unroll
    for (int nt = 0; nt < 2; ++nt)
#pragma unroll
      for (int i = 0; i < 16; ++i) acc[mt][nt][i] = 0.0f;

  for (int k0 = 0; k0 < 512; k0 += 32) {
    stage_region<128>(gBh + k0, ldsBh, wid, lane);
    stage_region<128>(gBl + k0, ldsBl, wid, lane);
#pragma unroll
    for (int r = 0; r < 4; ++r) {
      int m = lm + 32 * r;
      float4 f = *(const float4*)(A + (size_t)(bm + m) * H + k0 + 4 * ls);
      short4 h4, l4;
      split2(f.x, h4.x, l4.x); split2(f.y, h4.y, l4.y);
      split2(f.z, h4.z, l4.z); split2(f.w, h4.w, l4.w);
      *(short4*)(ldsAh + m * 32 + 4 * ls) = h4;
      *(short4*)(ldsAl + m * 32 + 4 * ls) = l4;
    }
    __syncthreads();
#pragma unroll
    for (int sub = 0; sub < 2; ++sub) {
      bf16x8 ah[2], al[2], bh[2], bl[2];
#pragma unroll
      for (int mt = 0; mt < 2; ++mt) {
        int r = wm * 64 + mt * 32 + (lane & 31);
        int off = r * 32 + sub * 16 + (lane >> 5) * 8;
        ah[mt] = *(const bf16x8*)(ldsAh + off);
        al[mt] = *(const bf16x8*)(ldsAl + off);
      }
#pragma unroll
      for (int nt = 0; nt < 2; ++nt) {
        int r = wn * 64 + nt * 32 + (lane & 31);
        int off = r * 32 + sub * 16 + (lane >> 5) * 8;
        bh[nt] = *(const bf16x8*)(ldsBh + off);
        bl[nt] = *(const bf16x8*)(ldsBl + off);
      }
#pragma unroll
      for (int mt = 0; mt < 2; ++mt)
#pragma unroll
        for (int nt = 0; nt < 2; ++nt) {
          acc[mt][nt] = __builtin_amdgcn_mfma_f32_32x32x16_bf16(ah[mt], bh[nt], acc[mt][nt], 0, 0, 0);
          acc[mt][nt] = __builtin_amdgcn_mfma_f32_32x32x16_bf16(ah[mt], bl[nt], acc[mt][nt], 0, 0, 0);
          acc[mt][nt] = __builtin_amdgcn_mfma_f32_32x32x16_bf16(al[mt], bh[nt], acc[mt][nt], 0, 0, 0);
        }
    }
    __syncthreads();
  }

#pragma unroll
  for (int mt = 0; mt < 2; ++mt)
#pragma unroll
    for (int nt = 0; nt < 2; ++nt) {
      int col = bn + wn * 64 + nt * 32 + (lane & 31);   // 0..5119
      int rbase = bm + wm * 64 + mt * 32 + 4 * (lane >> 5);
      int dd = col / 20, j = col - dd * 20;
#pragma unroll
      for (int reg = 0; reg < 16; ++reg) {
        int row = rbase + (reg & 3) + 8 * (reg >> 2);
        float v = acc[mt][nt][reg] + bf[dd * HEADW + 10 + j];
        if (j >= 10) v = (fmaxf(v, 0.0f) + log1pf(expf(-fabsf(v)))) + 0.001f;
        headout[(size_t)row * NFIN + dd * NOUT + 10 + j] = v;
      }
    }
}

// ---------------- tail compaction -----------------------------------------
// Observed entries (q==0): all three outputs are exactly 0 (ref multiplies
// by query) -> write zeros, no RNG. Unobserved idx appended to a work list.
__global__ __launch_bounds__(256) void init_counter(int* counter) {
  if (threadIdx.x == 0 && blockIdx.x == 0) *counter = 0;
}

__global__ __launch_bounds__(256) void compact_zero(const float* __restrict__ mask,
                                                    float* __restrict__ out_ll,
                                                    float* __restrict__ out_s,
                                                    float* __restrict__ out_mean,
                                                    int* __restrict__ list,
                                                    int* __restrict__ counter) {
  int idx = blockIdx.x * 256 + threadIdx.x;
  if (idx >= ND) return;
  if (mask[idx] != 0.0f) {   // observed -> q = 0 -> outputs all zero
    int b = idx >> 8, d = idx & (D - 1);
    out_ll[idx] = 0.0f;
    out_mean[idx] = 0.0f;
#pragma unroll
    for (int s = 0; s < S; ++s) out_s[((size_t)b * S + s) * D + d] = 0.0f;
  } else {
    int pos = atomicAdd(counter, 1);   // compiler aggregates per-wave (G12)
    list[pos] = idx;
  }
}

// ---------------- fused tail on compacted list (R6 arithmetic, q==1) -----
__global__ __launch_bounds__(256) void fused_tail(const float* __restrict__ head,
                                                  const float* __restrict__ x,
                                                  const float* __restrict__ mask,
                                                  const int* __restrict__ list,
                                                  const int* __restrict__ counter,
                                                  float* __restrict__ out_ll,
                                                  float* __restrict__ out_s,
                                                  float* __restrict__ out_mean,
                                                  uint32_t kc0, uint32_t kc1,
                                                  uint32_t kn0, uint32_t kn1) {
  int i = blockIdx.x * 256 + threadIdx.x;
  if (i >= *counter) return;
  int idx = list[i];
  int b = idx >> 8, d = idx & (D - 1);
  const float* hp = head + (size_t)idx * NOUT;
  float lg[K], mn[K], sc[K];
#pragma unroll
  for (int k = 0; k < K; ++k) { lg[k] = hp[k]; mn[k] = hp[K + k]; sc[k] = hp[2 * K + k]; }
  float q = 1.0f - mask[idx];          // == 1.0 exactly on this list
  float xu = x[idx] * q;
  // ---- ll + mean (verbatim R5/R6) ----
  float m = lg[0];
#pragma unroll
  for (int k = 1; k < K; ++k) m = fmaxf(m, lg[k]);
  float e[K];
  float sum = 0.0f;
#pragma unroll
  for (int k = 0; k < K; ++k) { e[k] = expf(lg[k] - m); sum += e[k]; }
  float lse = logf(sum);
  float a[K];
  float amax = -3.402823466e38f;
#pragma unroll
  for (int k = 0; k < K; ++k) {
    float z = (xu - mn[k]) / sc[k];
    float cll = -0.5f * z * z - logf(sc[k]) - 0.9189385332046727f;
    float lw = (lg[k] - m) - lse;
    a[k] = lw + cll;
    amax = fmaxf(amax, a[k]);
  }
  float s2 = 0.0f;
#pragma unroll
  for (int k = 0; k < K; ++k) s2 += expf(a[k] - amax);
  out_ll[idx] = (logf(s2) + amax) * q;
  float pm = 0.0f;
#pragma unroll
  for (int k = 0; k < K; ++k) pm += (e[k] / sum) * mn[k];
  out_mean[idx] = pm * q;
  // ---- samples: transformed categorical (frozen R6 numerics) ----
  float inv_e[K];
#pragma unroll
  for (int k = 0; k < K; ++k) inv_e[k] = 1.0f / e[k];
  for (int s = 0; s < S; ++s) {
    uint32_t t32 = (uint32_t)s * (uint32_t)ND + (uint32_t)idx;
    uint32_t base = t32 * (uint32_t)K;
    int best = 0;
    float rbest = 3.402823466e38f;
#pragma unroll
    for (int k = 0; k < K; ++k) {
      uint32_t bits = rb32(kc0, kc1, base + (uint32_t)k);
      float u = u01_from_bits(bits);
      float wv = -__log2f(u);              // hw v_log_f32; u=0 -> +inf (never wins)
      float r = wv * inv_e[k];
      if (r < rbest) { rbest = r; best = k; }  // first-min == reference first-max
    }
    uint32_t ebits = rb32(kn0, kn1, t32);
    float f = u01_from_bits(ebits);
    float r2 = f * 2.0f + (-0.99999994f);
    r2 = fmaxf(r2, -0.99999994f);
    float eps = 1.4142135623730951f * erfinv_f32(r2);
    out_s[((size_t)b * S + s) * D + d] = (mn[best] + sc[best] * eps) * q;
  }
}

// ---------------- launch ----------------
extern "C" void kernel_launch(void* const* d_in, const int* in_sizes, int n_in,
                              void* d_out, int out_size, void* d_ws, size_t ws_size,
                              hipStream_t stream) {
  const float* x    = (const float*)d_in[0];
  const float* mask = (const float*)d_in[1];
  const float* W_in = (const float*)d_in[2];
  const float* b_in = (const float*)d_in[3];
  const float* W1   = (const float*)d_in[4];
  const float* b1   = (const float*)d_in[5];
  const float* W2   = (const float*)d_in[6];
  const float* b2   = (const float*)d_in[7];
  const float* Wf   = (const float*)d_in[8];
  const float* bf   = (const float*)d_in[9];

  // workspace: head 125,829,120 + h 8,388,608 + wsgL 5,242,880
  //          + wms_h 5,242,880 + wms_l 5,242,880 + counter 4
  //          = 149,946,372 B (fits R1-proven cap). list aliases wsgL
  //          (wsgL dead after gemm_logits; compact runs after it).
  char* w = (char*)d_ws;
  float* head   = (float*)w;                     // B*7680 f32
  float* xcat   = head;                          // alias: dead after gemm0
  float* t      = head;                          // alias: dead before fin
  float* h      = (float*)(w + 125829120);       // B*512 f32 (live through fin)
  float* wsgL   = (float*)(w + 134217728);       // 512*2560 f32 logit weights
  int*   list   = (int*)(w + 134217728);         // alias wsgL: ND ints (4 MB)
  short* wms_h  = (short*)(w + 139460608);       // 5120*512 bf16
  short* wms_l  = (short*)(w + 144703488);       // 5120*512 bf16
  int*   counter = (int*)(w + 149946368);        // 4 B

  float* out_ll   = (float*)d_out;               // (B,D)
  float* out_s    = out_ll + (size_t)ND;         // (B,S,D)
  float* out_mean = out_s + (size_t)ND * S;      // (B,D)

  wgatherL<<<dim3(NLOG / 256, 512), 256, 0, stream>>>(Wf, wsgL);
  wsplit_ms<<<dim3(NMS / 32, 512 / 32), 256, 0, stream>>>(Wf, wms_h, wms_l);

  prep_kernel<<<(B * 2 * D) / 256, 256, 0, stream>>>(x, mask, xcat);

  dim3 gtr(H / 64, B / 64);  // (8, 64) = 512 blocks, 2 per CU
  gemm_trunk<0, 0><<<gtr, 128, 0, stream>>>(xcat, W_in, b_in, nullptr, h);
  for (int l = 0; l < NL; ++l) {
    gemm_trunk<1, 0><<<gtr, 128, 0, stream>>>(h, W1 + (size_t)l * H * H,
                                              b1 + (size_t)l * H, nullptr, t);
    gemm_trunk<1, 1><<<gtr, 128, 0, stream>>>(t, W2 + (size_t)l * H * H,
                                              b2 + (size_t)l * H, h, h);
  }

  gemm_logits<<<dim3(NLOG / 128, B / 128), 256, 0, stream>>>(h, wsgL, bf, head);
  gemm_ms<<<dim3(NMS / 128, B / 128), 256, 0, stream>>>(h, wms_h, wms_l, bf, head);

  // compaction (after gemm_logits: list overwrites wsgL)
  init_counter<<<1, 256, 0, stream>>>(counter);
  compact_zero<<<ND / 256, 256, 0, stream>>>(mask, out_ll, out_s, out_mean,
                                             list, counter);

  uint32_t kc0, kc1, kn0, kn1;
  threefry2x32(0u, 1234u, 0u, 0u, kc0, kc1);
  threefry2x32(0u, 1234u, 0u, 1u, kn0, kn1);
  fused_tail<<<ND / 256, 256, 0, stream>>>(head, x, mask, list, counter,
                                           out_ll, out_s, out_mean,
                                           kc0, kc1, kn0, kn1);
}

// Round 8
// 1213.004 us; speedup vs baseline: 1.1682x; 1.1289x over previous
//
#include <hip/hip_runtime.h>
#include <cstdint>

#define B 4096
#define D 256
#define H 512
#define K 10
#define NL 4
#define S 10
#define NOUT 30           // used head columns per d (3*K); tail C=64 unused
#define HEADW 94          // 3*K + C
#define ND (B*D)          // 1048576
#define NFIN 7680         // D*NOUT
#define NLOG 2560         // D*K   logits columns (exact fp32)
#define NMS  5120         // D*2K  means+scales columns (MFMA path)

typedef __bf16 bf16x8 __attribute__((ext_vector_type(8)));
typedef float  f32x16 __attribute__((ext_vector_type(16)));

// ---------------- threefry2x32 (JAX-exact) ----------------
__host__ __device__ inline void threefry2x32(uint32_t k0, uint32_t k1,
                                             uint32_t x0, uint32_t x1,
                                             uint32_t& o0, uint32_t& o1) {
  uint32_t ks2 = k0 ^ k1 ^ 0x1BD11BDAu;
#define TF_ROT(x, r) (((x) << (r)) | ((x) >> (32 - (r))))
#define TF_RND(r) { x0 += x1; x1 = TF_ROT(x1, r); x1 ^= x0; }
  x0 += k0; x1 += k1;
  TF_RND(13) TF_RND(15) TF_RND(26) TF_RND(6)
  x0 += k1; x1 += ks2 + 1u;
  TF_RND(17) TF_RND(29) TF_RND(16) TF_RND(24)
  x0 += ks2; x1 += k0 + 2u;
  TF_RND(13) TF_RND(15) TF_RND(26) TF_RND(6)
  x0 += k0; x1 += k1 + 3u;
  TF_RND(17) TF_RND(29) TF_RND(16) TF_RND(24)
  x0 += k1; x1 += ks2 + 4u;
  TF_RND(13) TF_RND(15) TF_RND(26) TF_RND(6)
  x0 += ks2; x1 += k0 + 5u;
  o0 = x0; o1 = x1;
#undef TF_RND
#undef TF_ROT
}

__device__ __forceinline__ uint32_t rb32(uint32_t k0, uint32_t k1, uint32_t idx) {
  uint32_t a, b;
  threefry2x32(k0, k1, 0u, idx, a, b);
  return a ^ b;
}

__device__ __forceinline__ float u01_from_bits(uint32_t bits) {
  return __uint_as_float((bits >> 9) | 0x3f800000u) - 1.0f;  // [0,1)
}

// XLA ErfInv32 (Giles single-precision polynomial)
__device__ __forceinline__ float erfinv_f32(float x) {
  float w = -log1pf(-x * x);
  float p;
  if (w < 5.0f) {
    w = w - 2.5f;
    p = 2.81022636e-08f;
    p = fmaf(p, w, 3.43273939e-07f);
    p = fmaf(p, w, -3.5233877e-06f);
    p = fmaf(p, w, -4.39150654e-06f);
    p = fmaf(p, w, 0.00021858087f);
    p = fmaf(p, w, -0.00125372503f);
    p = fmaf(p, w, -0.00417768164f);
    p = fmaf(p, w, 0.246640727f);
    p = fmaf(p, w, 1.50140941f);
  } else {
    w = sqrtf(w) - 3.0f;
    p = -0.000200214257f;
    p = fmaf(p, w, 0.000100950558f);
    p = fmaf(p, w, 0.00134934322f);
    p = fmaf(p, w, -0.00367342844f);
    p = fmaf(p, w, 0.00573950773f);
    p = fmaf(p, w, -0.0076224613f);
    p = fmaf(p, w, 0.00943887047f);
    p = fmaf(p, w, 1.00167406f);
    p = fmaf(p, w, 2.83297682f);
  }
  return p * x;
}

// ---------------- bf16 split helpers (R2-verified) ----------------
__device__ __forceinline__ unsigned short bf16_rne(float x) {
  uint32_t u = __float_as_uint(x);
  uint32_t r = u + 0x7fffu + ((u >> 16) & 1u);
  return (unsigned short)(r >> 16);
}

__device__ __forceinline__ void split2(float x, short& hi, short& lo) {
  unsigned short hb = bf16_rne(x);
  float hf = __uint_as_float((uint32_t)hb << 16);
  hi = (short)hb;
  lo = (short)bf16_rne(x - hf);
}

// ---------------- async global->LDS (16B/lane) ----------------
__device__ __forceinline__ void gload16(const void* g, void* l) {
  __builtin_amdgcn_global_load_lds(
      (const __attribute__((address_space(1))) void*)g,
      (__attribute__((address_space(3))) void*)l, 16, 0, 0);
}

// stage ROWS x 32 bf16 tile (row-major, 64B rows) from global [rows][512]
template <int ROWS>
__device__ __forceinline__ void stage_region(const short* __restrict__ g,
                                             short* l, int wid, int lane) {
#pragma unroll
  for (int c = wid; c < ROWS / 16; c += 4) {
    const short* gp = g + (size_t)(c * 16 + (lane >> 2)) * 512 + (lane & 3) * 8;
    gload16(gp, l + c * 512);
  }
}

// ---------------- prep: xcat = [x*mask, mask]  (bit-identical to R1) ------
__global__ __launch_bounds__(256) void prep_kernel(const float* __restrict__ x,
                                                   const float* __restrict__ mask,
                                                   float* __restrict__ xcat) {
  int i = blockIdx.x * 256 + threadIdx.x;  // over B*512
  if (i >= B * 2 * D) return;
  int b = i >> 9, c = i & 511;
  float v = (c < D) ? x[b * D + c] * mask[b * D + c] : mask[b * D + (c - D)];
  xcat[i] = v;
}

// ---------------- logit weight gather: wsgL[k][c] = Wf[k][(c/10)*94 + c%10]
__global__ __launch_bounds__(256) void wgatherL(const float* __restrict__ Wf,
                                                float* __restrict__ wsgL) {
  int c = blockIdx.x * 256 + threadIdx.x;  // 0..2559
  int k = blockIdx.y;                      // 0..511
  int dd = c / K, j = c - dd * K;
  wsgL[(size_t)k * NLOG + c] = Wf[(size_t)k * (D * HEADW) + dd * HEADW + j];
}

// ---- MS weight transpose + 2-split: Wf[512][24064] -> wms hi/lo [5120][512]
__global__ __launch_bounds__(256) void wsplit_ms(const float* __restrict__ Wf,
                                                 short* __restrict__ whi,
                                                 short* __restrict__ wlo) {
  __shared__ float tile[32][33];
  int n0 = blockIdx.x * 32, k0 = blockIdx.y * 32;
  int tx = threadIdx.x & 31, ty = threadIdx.x >> 5;  // 32 x 8
#pragma unroll
  for (int r = 0; r < 4; ++r) {
    int k = k0 + ty + r * 8;
    int n = n0 + tx;
    int dd = n / 20, j = n - dd * 20;
    tile[ty + r * 8][tx] = Wf[(size_t)k * (D * HEADW) + dd * HEADW + 10 + j];
  }
  __syncthreads();
#pragma unroll
  for (int r = 0; r < 4; ++r) {
    int n = n0 + ty + r * 8;
    int k = k0 + tx;
    float v = tile[tx][ty + r * 8];
    short hb, lb;
    split2(v, hb, lb);
    whi[(size_t)n * 512 + k] = hb;
    wlo[(size_t)n * 512 + k] = lb;
  }
}

// ---------------- fp32 trunk GEMM (bit-identical chains to R1/R4) --------
// C(4096x512) = [relu?](A) @ W(512x512) + bias [+ res]
// 64x64 tile, 256 threads, 4x4/thread (R4-proven), BK=64 (half the barrier
// drains of R4). Per-output: ONE sequential fmaf chain over ascending k.
template <int RELU, int RES>
__global__ __launch_bounds__(256) void gemm_trunk(const float* __restrict__ A,
                                                  const float* __restrict__ W,
                                                  const float* __restrict__ bias,
                                                  const float* res, float* C) {
  __shared__ float As[64 * 68];  // [k][m], stride 68 (272B, 16B-aligned)
  __shared__ float Ws[64 * 64];  // [k][n], stride 64
  const int tid = threadIdx.x;
  const int lane = tid & 63, wid = tid >> 6;
  const int tx = tid & 15, ty = tid >> 4;
  const int bm = blockIdx.y * 64, bn = blockIdx.x * 64;
  const int ls = tid & 15, lm = tid >> 4;  // A-load: k-slot(16), row(16)

  float acc[4][4] = {};

  for (int k0 = 0; k0 < H; k0 += 64) {
    // B: direct global->LDS, [k][n]; 16 chunks of 4 rows, 4 waves
#pragma unroll
    for (int c = wid; c < 16; c += 4) {
      gload16(W + (size_t)(k0 + c * 4 + (lane >> 4)) * H + bn + (lane & 15) * 4,
              Ws + c * 256 + lane * 4);
    }
    // A: load float4 along k, transpose into [k][m]
#pragma unroll
    for (int r = 0; r < 4; ++r) {
      int m = lm + 16 * r;
      float4 f = *(const float4*)(A + (size_t)(bm + m) * H + k0 + 4 * ls);
      if (RELU) {
        f.x = fmaxf(f.x, 0.0f); f.y = fmaxf(f.y, 0.0f);
        f.z = fmaxf(f.z, 0.0f); f.w = fmaxf(f.w, 0.0f);
      }
      As[(4 * ls + 0) * 68 + m] = f.x;
      As[(4 * ls + 1) * 68 + m] = f.y;
      As[(4 * ls + 2) * 68 + m] = f.z;
      As[(4 * ls + 3) * 68 + m] = f.w;
    }
    __syncthreads();
#pragma unroll
    for (int kk = 0; kk < 64; ++kk) {
      float4 a4 = *(const float4*)(As + kk * 68 + ty * 4);
      float4 b4 = *(const float4*)(Ws + kk * 64 + tx * 4);
      float a[4] = {a4.x, a4.y, a4.z, a4.w};
      float b[4] = {b4.x, b4.y, b4.z, b4.w};
#pragma unroll
      for (int i = 0; i < 4; ++i)
#pragma unroll
        for (int j = 0; j < 4; ++j) acc[i][j] = fmaf(a[i], b[j], acc[i][j]);
    }
    __syncthreads();
  }
#pragma unroll
  for (int i = 0; i < 4; ++i) {
    int row = bm + ty * 4 + i;
#pragma unroll
    for (int j = 0; j < 4; ++j) {
      int col = bn + tx * 4 + j;
      float v = acc[i][j] + bias[col];
      if (RES) v = res[(size_t)row * H + col] + v;  // same order as R1
      C[(size_t)row * H + col] = v;
    }
  }
}

// ---------------- FUSED head GEMM: logits (fp32, exact) + ms (MFMA) ------
// grid (60, 32): blockIdx.x < 20 -> logits 128-col tile (R7 code verbatim,
// bit-identical chains); else -> ms 128-col tile (R7 MFMA code verbatim).
// MFMA blocks co-scheduled with VALU blocks on a CU overlap (m114).
__global__ __launch_bounds__(256) void gemm_head(const float* __restrict__ A,
                                                 const float* __restrict__ Wg,
                                                 const short* __restrict__ Bh,
                                                 const short* __restrict__ Bl,
                                                 const float* __restrict__ bf,
                                                 float* __restrict__ headout) {
  __shared__ __align__(16) float smem[8448];  // 33792 B shared by both paths
  const int tid = threadIdx.x;
  const int lane = tid & 63, wid = tid >> 6;
  const int bm = blockIdx.y * 128;

  if (blockIdx.x < 20) {
    // ---------- logits path (exact fp32; frozen fmaf chains) ----------
    float* As = smem;          // 32*136
    float* Ws = smem + 4352;   // 32*128
    const int tx = tid & 15, ty = tid >> 4;
    const int bn = blockIdx.x * 128;
    const int ls = tid & 7, lm = tid >> 3;

    float acc[8][8] = {};

    for (int k0 = 0; k0 < H; k0 += 32) {
#pragma unroll
      for (int c = wid; c < 16; c += 4) {
        gload16(Wg + (size_t)(k0 + c * 2 + (lane >> 5)) * NLOG + bn + (lane & 31) * 4,
                Ws + c * 256 + lane * 4);
      }
#pragma unroll
      for (int r = 0; r < 4; ++r) {
        int m = lm + 32 * r;
        float4 f = *(const float4*)(A + (size_t)(bm + m) * H + k0 + 4 * ls);
        As[(4 * ls + 0) * 136 + m] = f.x;
        As[(4 * ls + 1) * 136 + m] = f.y;
        As[(4 * ls + 2) * 136 + m] = f.z;
        As[(4 * ls + 3) * 136 + m] = f.w;
      }
      __syncthreads();
#pragma unroll
      for (int kk = 0; kk < 32; ++kk) {
        float a[8], b[8];
        *(float4*)(a + 0) = *(const float4*)(As + kk * 136 + ty * 8);
        *(float4*)(a + 4) = *(const float4*)(As + kk * 136 + ty * 8 + 4);
        *(float4*)(b + 0) = *(const float4*)(Ws + kk * 128 + tx * 8);
        *(float4*)(b + 4) = *(const float4*)(Ws + kk * 128 + tx * 8 + 4);
#pragma unroll
        for (int i = 0; i < 8; ++i)
#pragma unroll
          for (int j = 0; j < 8; ++j) acc[i][j] = fmaf(a[i], b[j], acc[i][j]);
      }
      __syncthreads();
    }
#pragma unroll
    for (int i = 0; i < 8; ++i) {
      int row = bm + ty * 8 + i;
#pragma unroll
      for (int j = 0; j < 8; ++j) {
        int c = bn + tx * 8 + j;           // 0..2559 logit col
        int dd = c / K, jj = c - dd * K;
        float v = acc[i][j] + bf[dd * HEADW + jj];
        headout[(size_t)row * NFIN + dd * NOUT + jj] = v;
      }
    }
  } else {
    // ---------- ms path (MFMA; R2/R5-verified, frozen) ----------
    short* lds = (short*)smem;   // uses 16384 B
    const int wm = wid >> 1, wn = wid & 1;
    const int bn = (blockIdx.x - 20) * 128;
    const int ls = tid & 7, lm = tid >> 3;

    short* ldsAh = lds;
    short* ldsAl = lds + 4096;
    short* ldsBh = lds + 8192;
    short* ldsBl = lds + 12288;

    const short* gBh = Bh + (size_t)bn * 512;
    const short* gBl = Bl + (size_t)bn * 512;

    f32x16 acc[2][2];
#pragma unroll
    for (int mt = 0; mt < 2; ++mt)
#pragma unroll
      for (int nt = 0; nt < 2; ++nt)
#pragma unroll
        for (int i = 0; i < 16; ++i) acc[mt][nt][i] = 0.0f;

    for (int k0 = 0; k0 < 512; k0 += 32) {
      stage_region<128>(gBh + k0, ldsBh, wid, lane);
      stage_region<128>(gBl + k0, ldsBl, wid, lane);
#pragma unroll
      for (int r = 0; r < 4; ++r) {
        int m = lm + 32 * r;
        float4 f = *(const float4*)(A + (size_t)(bm + m) * H + k0 + 4 * ls);
        short4 h4, l4;
        split2(f.x, h4.x, l4.x); split2(f.y, h4.y, l4.y);
        split2(f.z, h4.z, l4.z); split2(f.w, h4.w, l4.w);
        *(short4*)(ldsAh + m * 32 + 4 * ls) = h4;
        *(short4*)(ldsAl + m * 32 + 4 * ls) = l4;
      }
      __syncthreads();
#pragma unroll
      for (int sub = 0; sub < 2; ++sub) {
        bf16x8 ah[2], al[2], bh[2], bl[2];
#pragma unroll
        for (int mt = 0; mt < 2; ++mt) {
          int r = wm * 64 + mt * 32 + (lane & 31);
          int off = r * 32 + sub * 16 + (lane >> 5) * 8;
          ah[mt] = *(const bf16x8*)(ldsAh + off);
          al[mt] = *(const bf16x8*)(ldsAl + off);
        }
#pragma unroll
        for (int nt = 0; nt < 2; ++nt) {
          int r = wn * 64 + nt * 32 + (lane & 31);
          int off = r * 32 + sub * 16 + (lane >> 5) * 8;
          bh[nt] = *(const bf16x8*)(ldsBh + off);
          bl[nt] = *(const bf16x8*)(ldsBl + off);
        }
#pragma unroll
        for (int mt = 0; mt < 2; ++mt)
#pragma unroll
          for (int nt = 0; nt < 2; ++nt) {
            acc[mt][nt] = __builtin_amdgcn_mfma_f32_32x32x16_bf16(ah[mt], bh[nt], acc[mt][nt], 0, 0, 0);
            acc[mt][nt] = __builtin_amdgcn_mfma_f32_32x32x16_bf16(ah[mt], bl[nt], acc[mt][nt], 0, 0, 0);
            acc[mt][nt] = __builtin_amdgcn_mfma_f32_32x32x16_bf16(al[mt], bh[nt], acc[mt][nt], 0, 0, 0);
          }
      }
      __syncthreads();
    }

#pragma unroll
    for (int mt = 0; mt < 2; ++mt)
#pragma unroll
      for (int nt = 0; nt < 2; ++nt) {
        int col = bn + wn * 64 + nt * 32 + (lane & 31);   // 0..5119
        int rbase = bm + wm * 64 + mt * 32 + 4 * (lane >> 5);
        int dd = col / 20, j = col - dd * 20;
#pragma unroll
        for (int reg = 0; reg < 16; ++reg) {
          int row = rbase + (reg & 3) + 8 * (reg >> 2);
          float v = acc[mt][nt][reg] + bf[dd * HEADW + 10 + j];
          if (j >= 10) v = (fmaxf(v, 0.0f) + log1pf(expf(-fabsf(v)))) + 0.001f;
          headout[(size_t)row * NFIN + dd * NOUT + 10 + j] = v;
        }
      }
  }
}

// ---------------- tail compaction -----------------------------------------
__global__ __launch_bounds__(256) void init_counter(int* counter) {
  if (threadIdx.x == 0 && blockIdx.x == 0) *counter = 0;
}

__global__ __launch_bounds__(256) void compact_zero(const float* __restrict__ mask,
                                                    float* __restrict__ out_ll,
                                                    float* __restrict__ out_s,
                                                    float* __restrict__ out_mean,
                                                    int* __restrict__ list,
                                                    int* __restrict__ counter) {
  int idx = blockIdx.x * 256 + threadIdx.x;
  if (idx >= ND) return;
  if (mask[idx] != 0.0f) {   // observed -> q = 0 -> outputs all zero
    int b = idx >> 8, d = idx & (D - 1);
    out_ll[idx] = 0.0f;
    out_mean[idx] = 0.0f;
#pragma unroll
    for (int s = 0; s < S; ++s) out_s[((size_t)b * S + s) * D + d] = 0.0f;
  } else {
    int pos = atomicAdd(counter, 1);   // compiler aggregates per-wave (G12)
    list[pos] = idx;
  }
}

// ---------------- fused tail on compacted list (frozen R6/R7 numerics) ---
__global__ __launch_bounds__(256) void fused_tail(const float* __restrict__ head,
                                                  const float* __restrict__ x,
                                                  const float* __restrict__ mask,
                                                  const int* __restrict__ list,
                                                  const int* __restrict__ counter,
                                                  float* __restrict__ out_ll,
                                                  float* __restrict__ out_s,
                                                  float* __restrict__ out_mean,
                                                  uint32_t kc0, uint32_t kc1,
                                                  uint32_t kn0, uint32_t kn1) {
  int i = blockIdx.x * 256 + threadIdx.x;
  if (i >= *counter) return;
  int idx = list[i];
  int b = idx >> 8, d = idx & (D - 1);
  const float* hp = head + (size_t)idx * NOUT;
  float lg[K], mn[K], sc[K];
#pragma unroll
  for (int k = 0; k < K; ++k) { lg[k] = hp[k]; mn[k] = hp[K + k]; sc[k] = hp[2 * K + k]; }
  float q = 1.0f - mask[idx];          // == 1.0 exactly on this list
  float xu = x[idx] * q;
  float m = lg[0];
#pragma unroll
  for (int k = 1; k < K; ++k) m = fmaxf(m, lg[k]);
  float e[K];
  float sum = 0.0f;
#pragma unroll
  for (int k = 0; k < K; ++k) { e[k] = expf(lg[k] - m); sum += e[k]; }
  float lse = logf(sum);
  float a[K];
  float amax = -3.402823466e38f;
#pragma unroll
  for (int k = 0; k < K; ++k) {
    float z = (xu - mn[k]) / sc[k];
    float cll = -0.5f * z * z - logf(sc[k]) - 0.9189385332046727f;
    float lw = (lg[k] - m) - lse;
    a[k] = lw + cll;
    amax = fmaxf(amax, a[k]);
  }
  float s2 = 0.0f;
#pragma unroll
  for (int k = 0; k < K; ++k) s2 += expf(a[k] - amax);
  out_ll[idx] = (logf(s2) + amax) * q;
  float pm = 0.0f;
#pragma unroll
  for (int k = 0; k < K; ++k) pm += (e[k] / sum) * mn[k];
  out_mean[idx] = pm * q;
  float inv_e[K];
#pragma unroll
  for (int k = 0; k < K; ++k) inv_e[k] = 1.0f / e[k];
  for (int s = 0; s < S; ++s) {
    uint32_t t32 = (uint32_t)s * (uint32_t)ND + (uint32_t)idx;
    uint32_t base = t32 * (uint32_t)K;
    int best = 0;
    float rbest = 3.402823466e38f;
#pragma unroll
    for (int k = 0; k < K; ++k) {
      uint32_t bits = rb32(kc0, kc1, base + (uint32_t)k);
      float u = u01_from_bits(bits);
      float wv = -__log2f(u);              // hw v_log_f32; u=0 -> +inf (never wins)
      float r = wv * inv_e[k];
      if (r < rbest) { rbest = r; best = k; }  // first-min == reference first-max
    }
    uint32_t ebits = rb32(kn0, kn1, t32);
    float f = u01_from_bits(ebits);
    float r2 = f * 2.0f + (-0.99999994f);
    r2 = fmaxf(r2, -0.99999994f);
    float eps = 1.4142135623730951f * erfinv_f32(r2);
    out_s[((size_t)b * S + s) * D + d] = (mn[best] + sc[best] * eps) * q;
  }
}

// ---------------- launch ----------------
extern "C" void kernel_launch(void* const* d_in, const int* in_sizes, int n_in,
                              void* d_out, int out_size, void* d_ws, size_t ws_size,
                              hipStream_t stream) {
  const float* x    = (const float*)d_in[0];
  const float* mask = (const float*)d_in[1];
  const float* W_in = (const float*)d_in[2];
  const float* b_in = (const float*)d_in[3];
  const float* W1   = (const float*)d_in[4];
  const float* b1   = (const float*)d_in[5];
  const float* W2   = (const float*)d_in[6];
  const float* b2   = (const float*)d_in[7];
  const float* Wf   = (const float*)d_in[8];
  const float* bf   = (const float*)d_in[9];

  // workspace: head 125,829,120 + h 8,388,608 + wsgL 5,242,880
  //          + wms_h 5,242,880 + wms_l 5,242,880 + counter 4
  //          = 149,946,372 B (fits cap). list aliases wsgL (dead after
  //          gemm_head; compact runs after it).
  char* w = (char*)d_ws;
  float* head   = (float*)w;                     // B*7680 f32
  float* xcat   = head;                          // alias: dead after gemm0
  float* t      = head;                          // alias: dead before fin
  float* h      = (float*)(w + 125829120);       // B*512 f32 (live through fin)
  float* wsgL   = (float*)(w + 134217728);       // 512*2560 f32 logit weights
  int*   list   = (int*)(w + 134217728);         // alias wsgL: ND ints (4 MB)
  short* wms_h  = (short*)(w + 139460608);       // 5120*512 bf16
  short* wms_l  = (short*)(w + 144703488);       // 5120*512 bf16
  int*   counter = (int*)(w + 149946368);        // 4 B

  float* out_ll   = (float*)d_out;               // (B,D)
  float* out_s    = out_ll + (size_t)ND;         // (B,S,D)
  float* out_mean = out_s + (size_t)ND * S;      // (B,D)

  wgatherL<<<dim3(NLOG / 256, 512), 256, 0, stream>>>(Wf, wsgL);
  wsplit_ms<<<dim3(NMS / 32, 512 / 32), 256, 0, stream>>>(Wf, wms_h, wms_l);

  prep_kernel<<<(B * 2 * D) / 256, 256, 0, stream>>>(x, mask, xcat);

  dim3 gtr(H / 64, B / 64);  // (8, 64) = 512 blocks, 2 per CU, 8 waves/CU
  gemm_trunk<0, 0><<<gtr, 256, 0, stream>>>(xcat, W_in, b_in, nullptr, h);
  for (int l = 0; l < NL; ++l) {
    gemm_trunk<1, 0><<<gtr, 256, 0, stream>>>(h, W1 + (size_t)l * H * H,
                                              b1 + (size_t)l * H, nullptr, t);
    gemm_trunk<1, 1><<<gtr, 256, 0, stream>>>(t, W2 + (size_t)l * H * H,
                                              b2 + (size_t)l * H, h, h);
  }

  // fused logits (fp32, x<20) + ms (MFMA, x>=20): 60x32 = 1920 blocks
  gemm_head<<<dim3(60, B / 128), 256, 0, stream>>>(h, wsgL, wms_h, wms_l, bf, head);

  // compaction (after gemm_head: list overwrites wsgL)
  init_counter<<<1, 256, 0, stream>>>(counter);
  compact_zero<<<ND / 256, 256, 0, stream>>>(mask, out_ll, out_s, out_mean,
                                             list, counter);

  uint32_t kc0, kc1, kn0, kn1;
  threefry2x32(0u, 1234u, 0u, 0u, kc0, kc1);
  threefry2x32(0u, 1234u, 0u, 1u, kn0, kn1);
  fused_tail<<<ND / 256, 256, 0, stream>>>(head, x, mask, list, counter,
                                           out_ll, out_s, out_mean,
                                           kc0, kc1, kn0, kn1);
}